// Round 1
// baseline (280.154 us; speedup 1.0000x reference)
//
#include <hip/hip_runtime.h>

#define N_NODES 140000
#define N_EDGES 2240000
#define NFEAT 128
#define NHID 128
#define N_FRAMES 14
#define NODES_PER_FRAME 10000

typedef __attribute__((ext_vector_type(8))) short frag_b16;
typedef __attribute__((ext_vector_type(4))) float f32x4;

__device__ __forceinline__ unsigned short f2bf(float f) {
    union { float f; unsigned int u; } v; v.f = f;
    unsigned int r = v.u + 0x7fffu + ((v.u >> 16) & 1u);   // RNE
    return (unsigned short)(r >> 16);
}
__device__ __forceinline__ float bf2f(unsigned short h) {
    union { unsigned int u; float f; } v; v.u = ((unsigned int)h) << 16;
    return v.f;
}

// ---------------------------------------------------------------------------
// Prep 1: WT_bf16[n*128 + k] = bf16(W[k*128 + n])   (transpose + convert)
// ---------------------------------------------------------------------------
__global__ void convert_wt(const float* __restrict__ W, unsigned short* __restrict__ WT) {
    int idx = blockIdx.x * blockDim.x + threadIdx.x;
    if (idx >= NFEAT * NHID) return;
    int k = idx >> 7, n = idx & 127;
    WT[n * 128 + k] = f2bf(W[idx]);
}

// ---------------------------------------------------------------------------
// Prep 2: CSR row offsets from sorted COO rows (no atomics needed downstream)
// ---------------------------------------------------------------------------
__global__ void build_row_ptr(const int* __restrict__ edge_row, int* __restrict__ row_ptr) {
    int e = blockIdx.x * blockDim.x + threadIdx.x;
    if (e >= N_EDGES) return;
    int r = edge_row[e];
    int prev = (e == 0) ? -1 : edge_row[e - 1];
    for (int q = prev + 1; q <= r; ++q) row_ptr[q] = e;
    if (e == N_EDGES - 1) {
        for (int q = r + 1; q <= N_NODES; ++q) row_ptr[q] = N_EDGES;
    }
}

// ---------------------------------------------------------------------------
// GEMM: support_bf16 = bf16(x @ W), via mfma_f32_16x16x32_bf16.
// Block = 256 thr = 4 waves, 64 rows/block (16 rows/wave), full 128 cols.
// A-frags: direct global fp32 load + in-reg bf16 convert (coalesced 128B/row).
// B-frags: W^T bf16 staged in LDS, padded stride 136 (16B-aligned b128 reads).
// ---------------------------------------------------------------------------
#define WT_STRIDE 136

__global__ __launch_bounds__(256) void gemm_kernel(
        const float* __restrict__ x, const unsigned short* __restrict__ WT,
        unsigned short* __restrict__ support) {
    __shared__ unsigned short wt_lds[128 * WT_STRIDE];

    // stage W^T (bf16) into LDS, 16B chunks
    const uint4* WTv = (const uint4*)WT;               // 2048 uint4
    for (int idx = threadIdx.x; idx < 2048; idx += 256) {
        uint4 d = WTv[idx];
        int elem = idx << 3;                           // ushort index
        int n = elem >> 7, k = elem & 127;
        *(uint4*)&wt_lds[n * WT_STRIDE + k] = d;
    }

    int wave = threadIdx.x >> 6;
    int lane = threadIdx.x & 63;
    int m = lane & 15;                                 // A-row / D-col within tile
    int q = lane >> 4;                                 // quad

    long row0 = (long)blockIdx.x * 64 + wave * 16;

    // A fragments: x[row0+m][ks*32 + q*8 .. +7], fp32 -> bf16
    int arow = (int)row0 + m;
    if (arow >= N_NODES) arow = N_NODES - 1;           // clamp (stores guarded)
    const float* xrow = x + (long)arow * 128 + q * 8;
    frag_b16 a[4];
#pragma unroll
    for (int ks = 0; ks < 4; ++ks) {
        float4 lo = *(const float4*)(xrow + ks * 32);
        float4 hi = *(const float4*)(xrow + ks * 32 + 4);
        frag_b16 af;
        af[0] = (short)f2bf(lo.x); af[1] = (short)f2bf(lo.y);
        af[2] = (short)f2bf(lo.z); af[3] = (short)f2bf(lo.w);
        af[4] = (short)f2bf(hi.x); af[5] = (short)f2bf(hi.y);
        af[6] = (short)f2bf(hi.z); af[7] = (short)f2bf(hi.w);
        a[ks] = af;
    }

    __syncthreads();

    if (row0 < N_NODES) {
        f32x4 acc[8];
#pragma unroll
        for (int t = 0; t < 8; ++t) acc[t] = (f32x4){0.f, 0.f, 0.f, 0.f};

#pragma unroll
        for (int t = 0; t < 8; ++t) {
            const unsigned short* bp = &wt_lds[(t * 16 + m) * WT_STRIDE + q * 8];
#pragma unroll
            for (int ks = 0; ks < 4; ++ks) {
                frag_b16 bfrag = *(const frag_b16*)(bp + ks * 32);
                acc[t] = __builtin_amdgcn_mfma_f32_16x16x32_bf16(a[ks], bfrag, acc[t], 0, 0, 0);
            }
        }

        // D: row = q*4 + r, col = t*16 + m
#pragma unroll
        for (int t = 0; t < 8; ++t) {
#pragma unroll
            for (int r = 0; r < 4; ++r) {
                long row = row0 + q * 4 + r;
                if (row < N_NODES)
                    support[row * 128 + t * 16 + m] = f2bf(acc[t][r]);
            }
        }
    }
}

// ---------------------------------------------------------------------------
// Fused: per output node i, aggregate edges of its 14 frame-nodes (CSR, no
// atomics), relu+bias, running max over frames, then log_softmax over 128.
// Block = 128 threads (thread = feature), grid = 10000.
// ---------------------------------------------------------------------------
__global__ __launch_bounds__(128) void agg_kernel(
        const unsigned short* __restrict__ support, const float* __restrict__ b,
        const float* __restrict__ edge_val, const int* __restrict__ edge_col,
        const int* __restrict__ row_ptr, float* __restrict__ out) {
    int i = blockIdx.x;
    int c = threadIdx.x;
    int lane = c & 63, wid = c >> 6;
    __shared__ float red[4];

    float bc = b[c];
    float mx = 0.f;                                    // relu => max >= 0

#pragma unroll 1
    for (int f = 0; f < N_FRAMES; ++f) {
        int n = f * NODES_PER_FRAME + i;
        int e0 = row_ptr[n];
        int e1 = row_ptr[n + 1];
        float acc = 0.f;
        int e = e0;
        for (; e + 3 < e1; e += 4) {
            int c0 = edge_col[e],     c1 = edge_col[e + 1];
            int c2 = edge_col[e + 2], c3 = edge_col[e + 3];
            float v0 = edge_val[e],     v1 = edge_val[e + 1];
            float v2 = edge_val[e + 2], v3 = edge_val[e + 3];
            float s0 = bf2f(support[(c0 << 7) | c]);
            float s1 = bf2f(support[(c1 << 7) | c]);
            float s2 = bf2f(support[(c2 << 7) | c]);
            float s3 = bf2f(support[(c3 << 7) | c]);
            acc += v0 * s0; acc += v1 * s1; acc += v2 * s2; acc += v3 * s3;
        }
        for (; e < e1; ++e)
            acc += edge_val[e] * bf2f(support[(edge_col[e] << 7) | c]);
        float h = acc + bc;
        h = h > 0.f ? h : 0.f;
        mx = fmaxf(mx, h);
    }

    // log_softmax over the 128 features (2 waves)
    float v = mx;
#pragma unroll
    for (int off = 32; off >= 1; off >>= 1) v = fmaxf(v, __shfl_xor(v, off));
    if (lane == 0) red[wid] = v;
    __syncthreads();
    float M = fmaxf(red[0], red[1]);

    float ex = __expf(mx - M);
    float s = ex;
#pragma unroll
    for (int off = 32; off >= 1; off >>= 1) s += __shfl_xor(s, off);
    if (lane == 0) red[2 + wid] = s;
    __syncthreads();
    float S = red[2] + red[3];

    out[(i << 7) | c] = (mx - M) - __logf(S);
}

// ---------------------------------------------------------------------------
extern "C" void kernel_launch(void* const* d_in, const int* in_sizes, int n_in,
                              void* d_out, int out_size, void* d_ws, size_t ws_size,
                              hipStream_t stream) {
    const float* x        = (const float*)d_in[0];
    const float* W        = (const float*)d_in[1];
    const float* b        = (const float*)d_in[2];
    const float* edge_val = (const float*)d_in[3];
    const int*   edge_row = (const int*)d_in[4];
    const int*   edge_col = (const int*)d_in[5];
    float* out = (float*)d_out;

    char* ws = (char*)d_ws;
    unsigned short* support = (unsigned short*)ws;                  // 35,840,000 B
    unsigned short* WT      = (unsigned short*)(ws + 35840000);     //     32,768 B
    int*            row_ptr = (int*)(ws + 35840000 + 32768);        //    560,004 B

    convert_wt<<<64, 256, 0, stream>>>(W, WT);
    build_row_ptr<<<(N_EDGES + 255) / 256, 256, 0, stream>>>(edge_row, row_ptr);
    gemm_kernel<<<(N_NODES + 63) / 64, 256, 0, stream>>>(x, WT, support);
    agg_kernel<<<NODES_PER_FRAME, 128, 0, stream>>>(support, b, edge_val, edge_col, row_ptr, out);
}